// Round 12
// baseline (860.614 us; speedup 1.0000x reference)
//
#include <hip/hip_runtime.h>
#include <math.h>

// Problem: B=2, T=2048, C=1024, H=16, D=64.
// Input/output dtype is sniffed at runtime (f32 vs bf16) — see detect_k.
#define Bdim 2
#define Tdim 2048
#define Cdim 1024
#define Hdim 16
#define Ddim 64

typedef unsigned short u16;
typedef __attribute__((ext_vector_type(8))) short bf16x8;  // 8 bf16 = 4 VGPRs
typedef __attribute__((ext_vector_type(4))) float f32x4;

__device__ __forceinline__ float b2f(u16 s){
  union { float f; unsigned u; } v; v.u = ((unsigned)s) << 16; return v.f;
}
__device__ __forceinline__ u16 f2b(float f){
  union { float f; unsigned u; } v; v.f = f;
  unsigned r = v.u + 0x7fffu + ((v.u >> 16) & 1u);  // RNE
  return (u16)(r >> 16);
}
// flag-dispatched scalar load of an INPUT tensor element (bf=1: bf16, bf=0: f32)
__device__ __forceinline__ float loadf(const void* p, size_t i, int bf){
  float r;
  if(bf) r = b2f(((const u16*)p)[i]);
  else   r = ((const float*)p)[i];
  return r;
}
__device__ __forceinline__ f32x4 mfma16(bf16x8 a, bf16x8 b, f32x4 c){
  return __builtin_amdgcn_mfma_f32_16x16x32_bf16(a, b, c, 0, 0, 0);
}

// ---------------- dtype sniffer -------------------------------------------
__global__ void detect_k(const u16* __restrict__ x, int* __restrict__ flag){
  if(threadIdx.x == 0 && blockIdx.x == 0){
    int sane = 0;
    for(int i = 0; i < 64; i++){
      int e = (x[i] >> 7) & 0xFF;
      sane += (e == 0 || (e >= 0x6E && e <= 0x8A)) ? 1 : 0;
    }
    *flag = (sane >= 56) ? 1 : 0;
  }
}

// ---------------- input convert (enc_hat -> bf16) -------------------------
__global__ __launch_bounds__(256) void cvt_k(const void* __restrict__ in,
    u16* __restrict__ out, int n, const int* __restrict__ flagp){
  int bf = *flagp;
  int i = blockIdx.x * 256 + threadIdx.x;
  if(i < n) out[i] = bf ? ((const u16*)in)[i] : f2b(((const float*)in)[i]);
}

// ---------------- weight transpose: in[K][N] -> out[N][K] (bf16) ----------
__global__ __launch_bounds__(256) void transpose_k(const void* __restrict__ in,
    u16* __restrict__ out, int K, int N, const int* __restrict__ flagp){
  __shared__ u16 tile[32][34];
  int bf = *flagp;
  int n0 = blockIdx.x * 32, k0 = blockIdx.y * 32;
  int tx = threadIdx.x & 31, ty = threadIdx.x >> 5;  // 32 x 8
  #pragma unroll
  for(int i = 0; i < 4; i++)
    tile[ty + i*8][tx] = f2b(loadf(in, (size_t)(k0 + ty + i*8) * N + n0 + tx, bf));
  __syncthreads();
  #pragma unroll
  for(int i = 0; i < 4; i++)
    out[(size_t)(n0 + ty + i*8) * K + k0 + tx] = tile[tx][ty + i*8];
}

// ---------------- LayerNorm over C=1024, one block per row ----------------
// SRC=0: input tensor (flag dtype). SRC=1: internal f32 (x2 residual).
template<int SRC>
__global__ __launch_bounds__(256) void ln_k(const void* __restrict__ xin,
    const void* __restrict__ g, const void* __restrict__ be,
    u16* __restrict__ out, const int* __restrict__ flagp){
  __shared__ float red[256];
  int bf = *flagp;
  int row = blockIdx.x, t = threadIdx.x;
  float v[4]; float s = 0.f;
  #pragma unroll
  for(int i = 0; i < 4; i++){
    size_t idx = (size_t)row * Cdim + t + i*256;
    v[i] = (SRC == 1) ? ((const float*)xin)[idx] : loadf(xin, idx, bf);
    s += v[i];
  }
  red[t] = s; __syncthreads();
  for(int o = 128; o > 0; o >>= 1){ if(t < o) red[t] += red[t+o]; __syncthreads(); }
  float mu = red[0] * (1.f / Cdim);
  __syncthreads();
  s = 0.f;
  #pragma unroll
  for(int i = 0; i < 4; i++){ float d = v[i] - mu; s += d*d; }
  red[t] = s; __syncthreads();
  for(int o = 128; o > 0; o >>= 1){ if(t < o) red[t] += red[t+o]; __syncthreads(); }
  float rstd = rsqrtf(red[0] * (1.f / Cdim) + 1e-5f);
  u16* orow = out + (size_t)row * Cdim;
  #pragma unroll
  for(int i = 0; i < 4; i++){
    int c = t + i*256;
    orow[c] = f2b((v[i] - mu) * rstd * loadf(g, c, bf) + loadf(be, c, bf));
  }
}

// ---------------- m93-style MFMA GEMM (round-8 measured-best form) --------
// 128x128 tile, BK=64, 4 waves each 64x64, register staging + ds_write_b128,
// LDS rows padded to 72 u16. Fully unrolled (round-7 lesson: rolled loops
// -> acc demoted to scratch). Round-11's m97-DMA variant measured WORSE
// (+24 us) — reverted.
enum { EPI_QKV = 0, EPI_RES = 1, EPI_GELU = 2, EPI_FINAL = 3 };

template<int EPI, int KK>
__global__ __launch_bounds__(256) void gemm_k(
    const u16* __restrict__ A, const u16* __restrict__ Bt, const void* __restrict__ bias,
    void* __restrict__ out0, void* __restrict__ out1, const void* __restrict__ res,
    int M, int N, int mofs, const int* __restrict__ flagp)
{
  const int K = KK;
  __shared__ u16 As[128 * 72];   // 18 KB
  __shared__ u16 Bs[128 * 72];   // 18 KB
  int bf = *flagp;
  int tid = threadIdx.x;
  int m0 = blockIdx.y * 128, n0 = blockIdx.x * 128;
  int w = tid >> 6, l = tid & 63;
  int lq = l & 15, lk = l >> 4;
  int m_off = (w & 1) * 64, n_off = (w >> 1) * 64;
  int srow = tid >> 3;           // 0..31
  int scol = (tid & 7) * 8;      // 0..56
  int br[4], ar[4];
  #pragma unroll
  for(int i = 0; i < 4; i++){
    ar[i] = m0 + srow + 32*i;
    br[i] = n0 + srow + 32*i;
    if(EPI == EPI_QKV && br[i] >= 1024) br[i] += 1024;  // skip unused K cols
  }
  f32x4 acc[4][4] = {};
  for(int k0 = 0; k0 < K; k0 += 64){
    bf16x8 av[4], bv[4];
    #pragma unroll
    for(int i = 0; i < 4; i++)
      av[i] = *(const bf16x8*)(A  + (size_t)ar[i] * K + k0 + scol);
    #pragma unroll
    for(int i = 0; i < 4; i++)
      bv[i] = *(const bf16x8*)(Bt + (size_t)br[i] * K + k0 + scol);
    __syncthreads();   // all waves done reading LDS from previous iter
    #pragma unroll
    for(int i = 0; i < 4; i++)
      *(bf16x8*)&As[(srow + 32*i) * 72 + scol] = av[i];
    #pragma unroll
    for(int i = 0; i < 4; i++)
      *(bf16x8*)&Bs[(srow + 32*i) * 72 + scol] = bv[i];
    __syncthreads();
    #pragma unroll
    for(int kk = 0; kk < 2; kk++){
      bf16x8 af[4], bfr[4];
      #pragma unroll
      for(int mb = 0; mb < 4; mb++)
        af[mb]  = *(const bf16x8*)&As[(m_off + mb*16 + lq) * 72 + kk*32 + lk*8];
      #pragma unroll
      for(int nb = 0; nb < 4; nb++)
        bfr[nb] = *(const bf16x8*)&Bs[(n_off + nb*16 + lq) * 72 + kk*32 + lk*8];
      #pragma unroll
      for(int mb = 0; mb < 4; mb++)
        #pragma unroll
        for(int nb = 0; nb < 4; nb++)
          acc[mb][nb] = mfma16(af[mb], bfr[nb], acc[mb][nb]);
    }
  }
  // epilogue: C/D layout row=(l>>4)*4+r, col=l&15
  #pragma unroll
  for(int mb = 0; mb < 4; mb++)
  #pragma unroll
  for(int nb = 0; nb < 4; nb++){
    #pragma unroll
    for(int r = 0; r < 4; r++){
      int m = m0 + m_off + mb*16 + lk*4 + r;
      int n = n0 + n_off + nb*16 + lq;
      float v = acc[mb][nb][r];
      if(EPI == EPI_QKV){
        int bsrc = (n < 1024) ? n : n + 1024;
        v += loadf(bias, bsrc, bf);
        int bb = m / Tdim, t = m % Tdim;
        if(n < 1024){  // Q -> (B,H,T,D)
          int h = n >> 6, d = n & 63;
          ((u16*)out0)[(((size_t)(bb*Hdim + h)*Tdim + t) << 6) + d] = f2b(v);
        } else {       // V -> transposed (B,H,D,T) for PV B-fragments
          int nv = n - 1024; int h = nv >> 6, d = nv & 63;
          ((u16*)out1)[((size_t)(bb*Hdim + h)*Ddim + d)*Tdim + t] = f2b(v);
        }
      } else if(EPI == EPI_RES){        // x2(f32) = x(INPUT) + A@W + bias
        v += loadf(bias, n, bf) + loadf(res, (size_t)m*N + n, bf);
        ((float*)out0)[(size_t)m*N + n] = v;
      } else if(EPI == EPI_GELU){       // exact gelu -> bf16
        v += loadf(bias, n, bf);
        float gl = 0.5f * v * (1.0f + erff(v * 0.70710678118f));
        ((u16*)out0)[(size_t)m*N + n] = f2b(gl);
      } else {                          // FINAL: x2(f32) + A@W + bias -> OUT
        v += loadf(bias, n, bf) + ((const float*)res)[(size_t)m*N + n];
        size_t oi = (size_t)(mofs + m) * N + n;
        if(bf) ((u16*)out0)[oi] = f2b(v);
        else   ((float*)out0)[oi] = v;
      }
    }
  }
}

// ---------------- fused LIF attention, split-st + XCD swizzle -------------
// Round-11 diagnosis: duration pinned at ~136 us across occupancy configs,
// HBM 2%, VALU 33% -> bound by L3/fabric: same-bh blocks scatter across
// XCDs, 16 MB aggregate E/V working set thrashes each 4 MB per-XCD L2.
// Swizzle: xcd = blockIdx&7 (round-robin dispatch), each XCD owns
// h in {2*xcd, 2*xcd+1} x both b -> per-XCD E/V set 1.5 MB <= 4 MB L2.
// 4 waves split the st range; partial num/den reduced via LDS.
__global__ __launch_bounds__(256) void attn_k(
    const u16* __restrict__ Q, const u16* __restrict__ Vt, const u16* __restrict__ E,
    const void* __restrict__ gain, const void* __restrict__ battn,
    u16* __restrict__ aout, const int* __restrict__ flagp)
{
  __shared__ float smem[5376];       // 21504 B: P bands (9216 B) then reused
  int bf = *flagp;
  int i = blockIdx.x;
  int xcd = i & 7, j = i >> 3;
  int h  = xcd*2 + (j & 1);
  int b  = (j >> 1) & 1;
  int rt = 127 - (j >> 2);           // LPT within each XCD
  int bh = b*16 + h;
  int tid = threadIdx.x, w = tid >> 6, l = tid & 63;
  int lq = l & 15, lk = l >> 4;
  u16* Pw = (u16*)smem + w * (16 * 72);   // wave-private P band, 16B-aligned
  const u16* Qb = Q  + (size_t)bh * Tdim * Ddim;
  const u16* Vb = Vt + (size_t)bh * Ddim * Tdim;
  const u16* Eh = E  + (size_t)h  * Tdim * Ddim;
  int qrow = rt * 16;
  int stmax = rt >> 2;             // causal: last 64-col tile index
  bf16x8 qf[2];
  #pragma unroll
  for(int ks = 0; ks < 2; ks++)
    qf[ks] = *(const bf16x8*)(Qb + (size_t)(qrow + lq) * Ddim + ks*32 + lk*8);
  float g4[4], b4[4];
  #pragma unroll
  for(int r = 0; r < 4; r++){
    int t = qrow + lk*4 + r;
    g4[r] = loadf(gain, h * Tdim + t, bf);
    b4[r] = loadf(battn, h * Tdim + t, bf);
  }
  bf16x8 onesf;
  #pragma unroll
  for(int j2 = 0; j2 < 8; j2++) onesf[j2] = (short)0x3F80;  // bf16 1.0
  f32x4 num[4] = {};
  f32x4 den4 = {0.f, 0.f, 0.f, 0.f};
  for(int st = w; st <= stmax; st += 4){
    f32x4 sc[4] = {};
    #pragma unroll
    for(int ks = 0; ks < 2; ks++){
      #pragma unroll
      for(int nb = 0; nb < 4; nb++){
        bf16x8 ef = *(const bf16x8*)(Eh + (size_t)(st*64 + nb*16 + lq) * Ddim + ks*32 + lk*8);
        sc[nb] = mfma16(qf[ks], ef, sc[nb]);
      }
    }
    #pragma unroll
    for(int nb = 0; nb < 4; nb++){
      #pragma unroll
      for(int r = 0; r < 4; r++){
        int sg = st*64 + nb*16 + lq;
        int qg = qrow + lk*4 + r;
        float I = fmaf(g4[r], sc[nb][r], b4[r]);
        float u = (I - 1.0f) * __builtin_amdgcn_rcpf(I);
        float L = __builtin_amdgcn_logf(u);
        float denom = fmaf(-0.013862944f, L, 0.002f);
        float e = __builtin_amdgcn_exp2f(0.18033688f * __builtin_amdgcn_rcpf(denom));
        float p = (I > 1.0000001f) ? e : 1.0f;
        p = (sg <= qg) ? p : 0.f;
        Pw[(lk*4 + r)*72 + nb*16 + lq] = f2b(p);
      }
    }
    // wave-private P band: in-wave LDS RAW ordered by compiler lgkmcnt waits
    #pragma unroll
    for(int ks = 0; ks < 2; ks++){
      bf16x8 pf = *(const bf16x8*)&Pw[lq*72 + ks*32 + lk*8];
      den4 = mfma16(pf, onesf, den4);   // rowsum -> denominator (C-layout rows)
      #pragma unroll
      for(int nb = 0; nb < 4; nb++){
        bf16x8 vf = *(const bf16x8*)(Vb + (size_t)(nb*16 + lq) * Tdim + st*64 + ks*32 + lk*8);
        num[nb] = mfma16(pf, vf, num[nb]);
      }
    }
  }
  // cross-wave reduction: Red[w][lane][21] floats (stride 21: conflict-free)
  __syncthreads();                 // all waves done with P bands
  float* Red = smem;
  int rb = (w*64 + l) * 21;
  #pragma unroll
  for(int nb = 0; nb < 4; nb++)
    #pragma unroll
    for(int r = 0; r < 4; r++) Red[rb + nb*4 + r] = num[nb][r];
  #pragma unroll
  for(int r = 0; r < 4; r++) Red[rb + 16 + r] = den4[r];
  __syncthreads();
  if(w != 0) return;
  float s[20];
  #pragma unroll
  for(int j2 = 0; j2 < 20; j2++)
    s[j2] = Red[l*21 + j2] + Red[(64+l)*21 + j2] + Red[(128+l)*21 + j2] + Red[(192+l)*21 + j2];
  #pragma unroll
  for(int nb = 0; nb < 4; nb++){
    #pragma unroll
    for(int r = 0; r < 4; r++){
      int t = qrow + lk*4 + r;
      int d = nb*16 + lq;
      float o = s[nb*4 + r] * __builtin_amdgcn_rcpf(s[16 + r]);
      aout[((size_t)b * Tdim + t) * Cdim + h * Ddim + d] = f2b(o);
    }
  }
}

// --------------------------------------------------------------------------
// Arena (52.25 MB peak — round-3..8 validated):
//   flag@0 | R0(8M): xn -> attn_out -> W1t | R1(8M): Wqkv_t -> Wout_t -> W2t
//   | x2(16M f32 residual) | R3a(8M): Q -> hn | R3b(8M): V^T -> gelu quarter
//   | Ebf(4M). MLP quartered over M (round-8 measured-best config).
extern "C" void kernel_launch(void* const* d_in, const int* in_sizes, int n_in,
                              void* d_out, int out_size, void* d_ws, size_t ws_size,
                              hipStream_t stream)
{
  const void* x      = d_in[0];
  const void* ln1_g  = d_in[1];
  const void* ln1_b  = d_in[2];
  const void* qkv_w  = d_in[3];
  const void* qkv_b  = d_in[4];
  const void* out_w  = d_in[5];
  const void* out_b  = d_in[6];
  const void* ln2_g  = d_in[7];
  const void* ln2_b  = d_in[8];
  const void* mlp_w1 = d_in[9];
  const void* mlp_b1 = d_in[10];
  const void* mlp_w2 = d_in[11];
  const void* mlp_b2 = d_in[12];
  const void* enc    = d_in[13];
  const void* gain   = d_in[14];
  const void* battn  = d_in[15];
  (void)in_sizes; (void)n_in; (void)out_size; (void)ws_size;

  const size_t MB = 1024 * 1024;
  char* ws = (char*)d_ws;
  int*   flag = (int*)(ws);
  u16*   R0   = (u16*)(ws + 256);
  u16*   R1   = (u16*)(ws + 256 + 8*MB);
  float* x2   = (float*)(ws + 256 + 16*MB);
  u16*   R3a  = (u16*)(ws + 256 + 32*MB);
  u16*   R3b  = (u16*)(ws + 256 + 40*MB);
  u16*   Ebf  = (u16*)(ws + 256 + 48*MB);

  dim3 blk(256);
  detect_k<<<1, 64, 0, stream>>>((const u16*)x, flag);
  ln_k<0><<<4096, blk, 0, stream>>>(x, ln1_g, ln1_b, R0, flag);
  transpose_k<<<dim3(3072/32, 1024/32), blk, 0, stream>>>(qkv_w, R1, 1024, 3072, flag);
  cvt_k<<<(Hdim*Tdim*Ddim)/256, blk, 0, stream>>>(enc, Ebf, Hdim*Tdim*Ddim, flag);
  gemm_k<EPI_QKV,1024><<<dim3(2048/128, 4096/128), blk, 0, stream>>>(
      R0, R1, qkv_b, R3a, R3b, nullptr, 4096, 2048, 0, flag);
  attn_k<<<dim3(32*128), blk, 0, stream>>>(R3a, R3b, Ebf, gain, battn, R0, flag);
  transpose_k<<<dim3(1024/32, 1024/32), blk, 0, stream>>>(out_w, R1, 1024, 1024, flag);
  gemm_k<EPI_RES,1024><<<dim3(1024/128, 4096/128), blk, 0, stream>>>(
      R0, R1, out_b, x2, nullptr, x, 4096, 1024, 0, flag);
  ln_k<1><<<4096, blk, 0, stream>>>(x2, ln2_g, ln2_b, R3a, flag);
  transpose_k<<<dim3(4096/32, 1024/32), blk, 0, stream>>>(mlp_w1, R0, 1024, 4096, flag);
  transpose_k<<<dim3(1024/32, 4096/32), blk, 0, stream>>>(mlp_w2, R1, 4096, 1024, flag);
  for(int q = 0; q < 4; q++){
    int ro = q * 1024;
    gemm_k<EPI_GELU,1024><<<dim3(4096/128, 1024/128), blk, 0, stream>>>(
        R3a + (size_t)ro*1024, R0, mlp_b1, R3b, nullptr, nullptr, 1024, 4096, 0, flag);
    gemm_k<EPI_FINAL,4096><<<dim3(1024/128, 1024/128), blk, 0, stream>>>(
        R3b, R1, mlp_b2, d_out, nullptr, x2 + (size_t)ro*1024, 1024, 1024, ro, flag);
  }
}

// Round 13
// 546.553 us; speedup vs baseline: 1.5746x; 1.5746x over previous
//
#include <hip/hip_runtime.h>
#include <math.h>

// Problem: B=2, T=2048, C=1024, H=16, D=64.
// Input/output dtype is sniffed at runtime (f32 vs bf16) — see detect_k.
#define Bdim 2
#define Tdim 2048
#define Cdim 1024
#define Hdim 16
#define Ddim 64

typedef unsigned short u16;
typedef __attribute__((ext_vector_type(8))) short bf16x8;  // 8 bf16 = 4 VGPRs
typedef __attribute__((ext_vector_type(4))) float f32x4;

__device__ __forceinline__ float b2f(u16 s){
  union { float f; unsigned u; } v; v.u = ((unsigned)s) << 16; return v.f;
}
__device__ __forceinline__ u16 f2b(float f){
  union { float f; unsigned u; } v; v.f = f;
  unsigned r = v.u + 0x7fffu + ((v.u >> 16) & 1u);  // RNE
  return (u16)(r >> 16);
}
// flag-dispatched scalar load of an INPUT tensor element (bf=1: bf16, bf=0: f32)
__device__ __forceinline__ float loadf(const void* p, size_t i, int bf){
  float r;
  if(bf) r = b2f(((const u16*)p)[i]);
  else   r = ((const float*)p)[i];
  return r;
}
__device__ __forceinline__ f32x4 mfma16(bf16x8 a, bf16x8 b, f32x4 c){
  return __builtin_amdgcn_mfma_f32_16x16x32_bf16(a, b, c, 0, 0, 0);
}

// ---------------- dtype sniffer -------------------------------------------
__global__ void detect_k(const u16* __restrict__ x, int* __restrict__ flag){
  if(threadIdx.x == 0 && blockIdx.x == 0){
    int sane = 0;
    for(int i = 0; i < 64; i++){
      int e = (x[i] >> 7) & 0xFF;
      sane += (e == 0 || (e >= 0x6E && e <= 0x8A)) ? 1 : 0;
    }
    *flag = (sane >= 56) ? 1 : 0;
  }
}

// ---------------- input convert (enc_hat -> bf16) -------------------------
__global__ __launch_bounds__(256) void cvt_k(const void* __restrict__ in,
    u16* __restrict__ out, int n, const int* __restrict__ flagp){
  int bf = *flagp;
  int i = blockIdx.x * 256 + threadIdx.x;
  if(i < n) out[i] = bf ? ((const u16*)in)[i] : f2b(((const float*)in)[i]);
}

// ---------------- weight transpose: in[K][N] -> out[N][K] (bf16) ----------
__global__ __launch_bounds__(256) void transpose_k(const void* __restrict__ in,
    u16* __restrict__ out, int K, int N, const int* __restrict__ flagp){
  __shared__ u16 tile[32][34];
  int bf = *flagp;
  int n0 = blockIdx.x * 32, k0 = blockIdx.y * 32;
  int tx = threadIdx.x & 31, ty = threadIdx.x >> 5;  // 32 x 8
  #pragma unroll
  for(int i = 0; i < 4; i++)
    tile[ty + i*8][tx] = f2b(loadf(in, (size_t)(k0 + ty + i*8) * N + n0 + tx, bf));
  __syncthreads();
  #pragma unroll
  for(int i = 0; i < 4; i++)
    out[(size_t)(n0 + ty + i*8) * K + k0 + tx] = tile[tx][ty + i*8];
}

// ---------------- LayerNorm over C=1024, one block per row ----------------
template<int SRC>
__global__ __launch_bounds__(256) void ln_k(const void* __restrict__ xin,
    const void* __restrict__ g, const void* __restrict__ be,
    u16* __restrict__ out, const int* __restrict__ flagp){
  __shared__ float red[256];
  int bf = *flagp;
  int row = blockIdx.x, t = threadIdx.x;
  float v[4]; float s = 0.f;
  #pragma unroll
  for(int i = 0; i < 4; i++){
    size_t idx = (size_t)row * Cdim + t + i*256;
    v[i] = (SRC == 1) ? ((const float*)xin)[idx] : loadf(xin, idx, bf);
    s += v[i];
  }
  red[t] = s; __syncthreads();
  for(int o = 128; o > 0; o >>= 1){ if(t < o) red[t] += red[t+o]; __syncthreads(); }
  float mu = red[0] * (1.f / Cdim);
  __syncthreads();
  s = 0.f;
  #pragma unroll
  for(int i = 0; i < 4; i++){ float d = v[i] - mu; s += d*d; }
  red[t] = s; __syncthreads();
  for(int o = 128; o > 0; o >>= 1){ if(t < o) red[t] += red[t+o]; __syncthreads(); }
  float rstd = rsqrtf(red[0] * (1.f / Cdim) + 1e-5f);
  u16* orow = out + (size_t)row * Cdim;
  #pragma unroll
  for(int i = 0; i < 4; i++){
    int c = t + i*256;
    orow[c] = f2b((v[i] - mu) * rstd * loadf(g, c, bf) + loadf(be, c, bf));
  }
}

// ---------------- m93-style MFMA GEMM (round-8 measured-best form) --------
// 128x128 tile, BK=64, 4 waves each 64x64, register staging + ds_write_b128,
// LDS rows padded to 72 u16, fully unrolled (rolled loops -> scratch, r7).
enum { EPI_QKV = 0, EPI_RES = 1, EPI_GELU = 2, EPI_FINAL = 3 };

template<int EPI, int KK>
__global__ __launch_bounds__(256) void gemm_k(
    const u16* __restrict__ A, const u16* __restrict__ Bt, const void* __restrict__ bias,
    void* __restrict__ out0, void* __restrict__ out1, const void* __restrict__ res,
    int M, int N, int mofs, const int* __restrict__ flagp)
{
  const int K = KK;
  __shared__ u16 As[128 * 72];   // 18 KB
  __shared__ u16 Bs[128 * 72];   // 18 KB
  int bf = *flagp;
  int tid = threadIdx.x;
  int m0 = blockIdx.y * 128, n0 = blockIdx.x * 128;
  int w = tid >> 6, l = tid & 63;
  int lq = l & 15, lk = l >> 4;
  int m_off = (w & 1) * 64, n_off = (w >> 1) * 64;
  int srow = tid >> 3;           // 0..31
  int scol = (tid & 7) * 8;      // 0..56
  int br[4], ar[4];
  #pragma unroll
  for(int i = 0; i < 4; i++){
    ar[i] = m0 + srow + 32*i;
    br[i] = n0 + srow + 32*i;
    if(EPI == EPI_QKV && br[i] >= 1024) br[i] += 1024;  // skip unused K cols
  }
  f32x4 acc[4][4] = {};
  for(int k0 = 0; k0 < K; k0 += 64){
    bf16x8 av[4], bv[4];
    #pragma unroll
    for(int i = 0; i < 4; i++)
      av[i] = *(const bf16x8*)(A  + (size_t)ar[i] * K + k0 + scol);
    #pragma unroll
    for(int i = 0; i < 4; i++)
      bv[i] = *(const bf16x8*)(Bt + (size_t)br[i] * K + k0 + scol);
    __syncthreads();   // all waves done reading LDS from previous iter
    #pragma unroll
    for(int i = 0; i < 4; i++)
      *(bf16x8*)&As[(srow + 32*i) * 72 + scol] = av[i];
    #pragma unroll
    for(int i = 0; i < 4; i++)
      *(bf16x8*)&Bs[(srow + 32*i) * 72 + scol] = bv[i];
    __syncthreads();
    #pragma unroll
    for(int kk = 0; kk < 2; kk++){
      bf16x8 af[4], bfr[4];
      #pragma unroll
      for(int mb = 0; mb < 4; mb++)
        af[mb]  = *(const bf16x8*)&As[(m_off + mb*16 + lq) * 72 + kk*32 + lk*8];
      #pragma unroll
      for(int nb = 0; nb < 4; nb++)
        bfr[nb] = *(const bf16x8*)&Bs[(n_off + nb*16 + lq) * 72 + kk*32 + lk*8];
      #pragma unroll
      for(int mb = 0; mb < 4; mb++)
        #pragma unroll
        for(int nb = 0; nb < 4; nb++)
          acc[mb][nb] = mfma16(af[mb], bfr[nb], acc[mb][nb]);
    }
  }
  // epilogue: C/D layout row=(l>>4)*4+r, col=l&15
  #pragma unroll
  for(int mb = 0; mb < 4; mb++)
  #pragma unroll
  for(int nb = 0; nb < 4; nb++){
    #pragma unroll
    for(int r = 0; r < 4; r++){
      int m = m0 + m_off + mb*16 + lk*4 + r;
      int n = n0 + n_off + nb*16 + lq;
      float v = acc[mb][nb][r];
      if(EPI == EPI_QKV){
        int bsrc = (n < 1024) ? n : n + 1024;
        v += loadf(bias, bsrc, bf);
        int bb = m / Tdim, t = m % Tdim;
        if(n < 1024){  // Q -> (B,H,T,D)
          int h = n >> 6, d = n & 63;
          ((u16*)out0)[(((size_t)(bb*Hdim + h)*Tdim + t) << 6) + d] = f2b(v);
        } else {       // V -> transposed (B,H,D,T) for PV B-fragments
          int nv = n - 1024; int h = nv >> 6, d = nv & 63;
          ((u16*)out1)[((size_t)(bb*Hdim + h)*Ddim + d)*Tdim + t] = f2b(v);
        }
      } else if(EPI == EPI_RES){        // x2(f32) = x(INPUT) + A@W + bias
        v += loadf(bias, n, bf) + loadf(res, (size_t)m*N + n, bf);
        ((float*)out0)[(size_t)m*N + n] = v;
      } else if(EPI == EPI_GELU){       // exact gelu -> bf16
        v += loadf(bias, n, bf);
        float gl = 0.5f * v * (1.0f + erff(v * 0.70710678118f));
        ((u16*)out0)[(size_t)m*N + n] = f2b(gl);
      } else {                          // FINAL: x2(f32) + A@W + bias -> OUT
        v += loadf(bias, n, bf) + ((const float*)res)[(size_t)m*N + n];
        size_t oi = (size_t)(mofs + m) * N + n;
        if(bf) ((u16*)out0)[oi] = f2b(v);
        else   ((float*)out0)[oi] = v;
      }
    }
  }
}

// ---------------- fused LIF attention (round-9/10 measured-best: 136 us) --
// ONE WAVE PER BLOCK (64 threads), 16 q-rows; grid 32 bh x 128 row-tiles,
// LPT (rt = 127 - blockIdx>>5). One-log LIF via hw transcendentals;
// denominator via MFMA ones-rowsum. Wave-private P band -> no barriers.
__global__ __launch_bounds__(64) void attn_k(
    const u16* __restrict__ Q, const u16* __restrict__ Vt, const u16* __restrict__ E,
    const void* __restrict__ gain, const void* __restrict__ battn,
    u16* __restrict__ aout, const int* __restrict__ flagp)
{
  __shared__ u16 P[16][72];  // row stride 144 B (multiple of 16)
  int bf = *flagp;
  int rt = 127 - (int)(blockIdx.x >> 5), bh = blockIdx.x & 31;
  int b = bh >> 4, h = bh & 15;
  int l = threadIdx.x & 63;
  int lq = l & 15, lk = l >> 4;
  const u16* Qb = Q  + (size_t)bh * Tdim * Ddim;
  const u16* Vb = Vt + (size_t)bh * Ddim * Tdim;
  const u16* Eh = E  + (size_t)h  * Tdim * Ddim;
  int qrow = rt * 16;
  int stmax = rt >> 2;             // causal: last 64-col tile index
  bf16x8 qf[2];
  #pragma unroll
  for(int ks = 0; ks < 2; ks++)
    qf[ks] = *(const bf16x8*)(Qb + (size_t)(qrow + lq) * Ddim + ks*32 + lk*8);
  float g4[4], b4[4];
  #pragma unroll
  for(int r = 0; r < 4; r++){
    int t = qrow + lk*4 + r;
    g4[r] = loadf(gain, h * Tdim + t, bf);
    b4[r] = loadf(battn, h * Tdim + t, bf);
  }
  bf16x8 onesf;
  #pragma unroll
  for(int j = 0; j < 8; j++) onesf[j] = (short)0x3F80;  // bf16 1.0
  f32x4 num[4] = {};
  f32x4 den4 = {0.f, 0.f, 0.f, 0.f};
  for(int st = 0; st <= stmax; st++){
    f32x4 sc[4] = {};
    #pragma unroll
    for(int ks = 0; ks < 2; ks++){
      #pragma unroll
      for(int nb = 0; nb < 4; nb++){
        bf16x8 ef = *(const bf16x8*)(Eh + (size_t)(st*64 + nb*16 + lq) * Ddim + ks*32 + lk*8);
        sc[nb] = mfma16(qf[ks], ef, sc[nb]);
      }
    }
    #pragma unroll
    for(int nb = 0; nb < 4; nb++){
      #pragma unroll
      for(int r = 0; r < 4; r++){
        int sg = st*64 + nb*16 + lq;
        int qg = qrow + lk*4 + r;
        float I = fmaf(g4[r], sc[nb][r], b4[r]);
        float u = (I - 1.0f) * __builtin_amdgcn_rcpf(I);
        float L = __builtin_amdgcn_logf(u);
        float denom = fmaf(-0.013862944f, L, 0.002f);
        float e = __builtin_amdgcn_exp2f(0.18033688f * __builtin_amdgcn_rcpf(denom));
        float p = (I > 1.0000001f) ? e : 1.0f;
        p = (sg <= qg) ? p : 0.f;
        P[lk*4 + r][nb*16 + lq] = f2b(p);
      }
    }
    // single-wave block: in-wave LDS RAW ordered by compiler lgkmcnt waits
    #pragma unroll
    for(int ks = 0; ks < 2; ks++){
      bf16x8 pf = *(const bf16x8*)&P[lq][ks*32 + lk*8];
      den4 = mfma16(pf, onesf, den4);   // rowsum -> denominator (C-layout rows)
      #pragma unroll
      for(int nb = 0; nb < 4; nb++){
        bf16x8 vf = *(const bf16x8*)(Vb + (size_t)(nb*16 + lq) * Tdim + st*64 + ks*32 + lk*8);
        num[nb] = mfma16(pf, vf, num[nb]);
      }
    }
  }
  float rden[4];
  #pragma unroll
  for(int r = 0; r < 4; r++) rden[r] = __builtin_amdgcn_rcpf(den4[r]);
  #pragma unroll
  for(int nb = 0; nb < 4; nb++){
    #pragma unroll
    for(int r = 0; r < 4; r++){
      int t = qrow + lk*4 + r;
      int d = nb*16 + lq;
      float o = num[nb][r] * rden[r];
      aout[((size_t)b * Tdim + t) * Cdim + h * Ddim + d] = f2b(o);
    }
  }
}

// --------------------------------------------------------------------------
// Arena (round-8 layout, the measured-best config):
//   flag@0 | R0(8M): xn -> attn_out -> W1t | R1(8M): Wqkv_t -> Wout_t -> W2t
//   | x2(16M f32) | R3a(8M): Q -> hn | R3b(8M): V^T -> gelu quarter | Ebf(4M)
//   | gbuf(32M) @52M iff ws_size >= 85MB -> FULL-M MLP (ran in round 8:
//   GELU 1024 blocks, FINAL 256 blocks — the 563 us path).
extern "C" void kernel_launch(void* const* d_in, const int* in_sizes, int n_in,
                              void* d_out, int out_size, void* d_ws, size_t ws_size,
                              hipStream_t stream)
{
  const void* x      = d_in[0];
  const void* ln1_g  = d_in[1];
  const void* ln1_b  = d_in[2];
  const void* qkv_w  = d_in[3];
  const void* qkv_b  = d_in[4];
  const void* out_w  = d_in[5];
  const void* out_b  = d_in[6];
  const void* ln2_g  = d_in[7];
  const void* ln2_b  = d_in[8];
  const void* mlp_w1 = d_in[9];
  const void* mlp_b1 = d_in[10];
  const void* mlp_w2 = d_in[11];
  const void* mlp_b2 = d_in[12];
  const void* enc    = d_in[13];
  const void* gain   = d_in[14];
  const void* battn  = d_in[15];
  (void)in_sizes; (void)n_in; (void)out_size;

  const size_t MB = 1024 * 1024;
  char* ws = (char*)d_ws;
  int*   flag = (int*)(ws);
  u16*   R0   = (u16*)(ws + 256);
  u16*   R1   = (u16*)(ws + 256 + 8*MB);
  float* x2   = (float*)(ws + 256 + 16*MB);
  u16*   R3a  = (u16*)(ws + 256 + 32*MB);
  u16*   R3b  = (u16*)(ws + 256 + 40*MB);
  u16*   Ebf  = (u16*)(ws + 256 + 48*MB);
  u16*   gbuf = (u16*)(ws + 256 + 52*MB);
  bool fullM = ws_size >= 85*MB;

  dim3 blk(256);
  detect_k<<<1, 64, 0, stream>>>((const u16*)x, flag);
  ln_k<0><<<4096, blk, 0, stream>>>(x, ln1_g, ln1_b, R0, flag);
  transpose_k<<<dim3(3072/32, 1024/32), blk, 0, stream>>>(qkv_w, R1, 1024, 3072, flag);
  cvt_k<<<(Hdim*Tdim*Ddim)/256, blk, 0, stream>>>(enc, Ebf, Hdim*Tdim*Ddim, flag);
  gemm_k<EPI_QKV,1024><<<dim3(2048/128, 4096/128), blk, 0, stream>>>(
      R0, R1, qkv_b, R3a, R3b, nullptr, 4096, 2048, 0, flag);
  attn_k<<<dim3(32*128), dim3(64), 0, stream>>>(R3a, R3b, Ebf, gain, battn, R0, flag);
  transpose_k<<<dim3(1024/32, 1024/32), blk, 0, stream>>>(out_w, R1, 1024, 1024, flag);
  gemm_k<EPI_RES,1024><<<dim3(1024/128, 4096/128), blk, 0, stream>>>(
      R0, R1, out_b, x2, nullptr, x, 4096, 1024, 0, flag);
  ln_k<1><<<4096, blk, 0, stream>>>(x2, ln2_g, ln2_b, R3a, flag);
  transpose_k<<<dim3(4096/32, 1024/32), blk, 0, stream>>>(mlp_w1, R0, 1024, 4096, flag);
  transpose_k<<<dim3(1024/32, 4096/32), blk, 0, stream>>>(mlp_w2, R1, 4096, 1024, flag);
  if(fullM){
    gemm_k<EPI_GELU,1024><<<dim3(4096/128, 4096/128), blk, 0, stream>>>(
        R3a, R0, mlp_b1, gbuf, nullptr, nullptr, 4096, 4096, 0, flag);
    gemm_k<EPI_FINAL,4096><<<dim3(1024/128, 4096/128), blk, 0, stream>>>(
        gbuf, R1, mlp_b2, d_out, nullptr, x2, 4096, 1024, 0, flag);
  } else {
    for(int q = 0; q < 4; q++){
      int ro = q * 1024;
      gemm_k<EPI_GELU,1024><<<dim3(4096/128, 1024/128), blk, 0, stream>>>(
          R3a + (size_t)ro*1024, R0, mlp_b1, R3b, nullptr, nullptr, 1024, 4096, 0, flag);
      gemm_k<EPI_FINAL,4096><<<dim3(1024/128, 1024/128), blk, 0, stream>>>(
          R3b, R1, mlp_b2, d_out, nullptr, x2 + (size_t)ro*1024, 1024, 1024, ro, flag);
    }
  }
}